// Round 8
// baseline (278.336 us; speedup 1.0000x reference)
//
#include <hip/hip_runtime.h>

// B=4, T=4096, D=1024. Inputs/outputs fp32. GEMM in bf16 MFMA.
// Pipeline: ln_conv -> gemm1 (+fused per-chunk scan aggregates) -> combine -> final -> gemm2.
// Numerics: la = log(alpha+1e-8) <= ~1e-8, so global max of cumsum ~= la[t=0] (error <= 4e-5);
// m is read from la row t=0 in combine; no max machinery anywhere.
// R8 = R6/R7 resubmitted verbatim (both failed at container bring-up: no timing fields =>
//     infra failure before kernel upload; kernel never ran). Race-free 4-phase lockstep
//     core: P1/P2 do all 24 ds_reads (each consumed by an MFMA in its own phase); P3/P4 do
//     all 8 stages + register-only MFMA; ONE counted vmcnt(8) per K-tile at P4 (tile t+1
//     landed, t+2 in flight; R2/R4-verified ledger). No sched_barrier / asm lgkm (R3 = m141
//     pinning regression). T2 swizzle (conflicts 0) + XCD chunking + setprio kept.
#define D_DIM 1024
#define B_DIM 4
#define T_DIM 4096
#define M_DIM (B_DIM * T_DIM)   // 16384 rows
#define CHUNK 32
#define NCHUNK (T_DIM / CHUNK)  // 128
#define NWAVE_C 16              // waves per combine block
#define SEG (NCHUNK / NWAVE_C)  // 8 chunks per wave in combine
#define NKT (D_DIM / 64)        // 16 K-tiles of 64

typedef unsigned short u16;
typedef __attribute__((ext_vector_type(8))) __bf16 bf16x8;
typedef __attribute__((ext_vector_type(4))) float f32x4;

__device__ __forceinline__ float bf2f(u16 u) {
    union { unsigned int i; float f; } v;
    v.i = ((unsigned int)u) << 16;
    return v.f;
}
__device__ __forceinline__ u16 f2bf(float f) {
    union { float f; unsigned int i; } v;
    v.f = f;
    unsigned int u = v.i;
    unsigned int r = (u + 0x7fffu + ((u >> 16) & 1u)) >> 16;
    return (u16)r;
}
__device__ __forceinline__ float fast_tanh(float v) {
    float e = __expf(2.f * v);
    return 1.f - 2.f / (e + 1.f);
}

#define GLOAD16(g, l)                                                   \
    __builtin_amdgcn_global_load_lds(                                   \
        (const __attribute__((address_space(1))) void*)(g),             \
        (__attribute__((address_space(3))) void*)(l), 16, 0, 0)

// Plain barrier between compiler memory fences: memory ops cannot cross (correctness),
// but instruction scheduling stays with the compiler (no sched_barrier -- m141/R3 lesson).
#define BAR()                                      \
    do {                                           \
        asm volatile("" ::: "memory");             \
        __builtin_amdgcn_s_barrier();              \
        asm volatile("" ::: "memory");             \
    } while (0)

#define WAITVM(N) asm volatile("s_waitcnt vmcnt(" #N ")" ::: "memory")

// ---------------- fused weight-convert (blocks 0..2047) + wave-per-row LayerNorm ----------
__global__ __launch_bounds__(256) void ln_conv_kernel(const float* __restrict__ x,
                                                      const float* __restrict__ w,
                                                      const float* __restrict__ b,
                                                      u16* __restrict__ xn,
                                                      const float* __restrict__ Wf,
                                                      const float* __restrict__ Wr,
                                                      u16* __restrict__ da,
                                                      u16* __restrict__ db) {
    int tid = threadIdx.x;
    if (blockIdx.x < 2048) {            // convert: 2 x 262144 float4s
        int i = blockIdx.x * 256 + tid;
        const float* s = (i < 262144) ? Wf : Wr;
        u16* dp = (i < 262144) ? da : db;
        int j = i & 262143;
        float4 v = ((const float4*)s)[j];
        ushort4 o;
        o.x = f2bf(v.x); o.y = f2bf(v.y); o.z = f2bf(v.z); o.w = f2bf(v.w);
        ((ushort4*)dp)[j] = o;
        return;
    }
    // LN: one wave per row, 4 rows per block, no __syncthreads
    int wv = tid >> 6, lane = tid & 63;
    int row = (blockIdx.x - 2048) * 4 + wv;
    const float4* xr = (const float4*)(x + (size_t)row * D_DIM);
    float4 xv[4];
    #pragma unroll
    for (int k = 0; k < 4; k++) xv[k] = xr[lane + 64 * k];
    float s = 0.f, s2 = 0.f;
    #pragma unroll
    for (int k = 0; k < 4; k++) {
        s  += xv[k].x + xv[k].y + xv[k].z + xv[k].w;
        s2 += xv[k].x * xv[k].x + xv[k].y * xv[k].y
            + xv[k].z * xv[k].z + xv[k].w * xv[k].w;
    }
    #pragma unroll
    for (int o = 1; o < 64; o <<= 1) {
        s  += __shfl_xor(s, o, 64);
        s2 += __shfl_xor(s2, o, 64);
    }
    float mu = s * (1.0f / D_DIM);
    float var = s2 * (1.0f / D_DIM) - mu * mu;
    float rs = rsqrtf(var + 1e-5f);
    ushort4* xo = (ushort4*)(xn + (size_t)row * D_DIM);
    #pragma unroll
    for (int k = 0; k < 4; k++) {
        float4 wv4 = ((const float4*)w)[lane + 64 * k];
        float4 bv4 = ((const float4*)b)[lane + 64 * k];
        ushort4 o;
        o.x = f2bf((xv[k].x - mu) * rs * wv4.x + bv4.x);
        o.y = f2bf((xv[k].y - mu) * rs * wv4.y + bv4.y);
        o.z = f2bf((xv[k].z - mu) * rs * wv4.z + bv4.z);
        o.w = f2bf((xv[k].w - mu) * rs * wv4.w + bv4.w);
        xo[lane + 64 * k] = o;
    }
}

// ---------------- 256x256 BK=64 4-phase lockstep GEMM core (fills acc[8][4]) -------------
// A [M][1024], B [N][1024] row-major bf16 (C = A.B^T slice). 512 thr = 8 waves (2m x 4n).
// LDS: [2 dbuf][256 rows][64 cols] per operand, 16B-slot XOR swizzle slot^=(row&7),
// staged via pre-swizzled GLOBAL source (linear gload_lds dest), un-swizzled on ds_read.
// Per K-tile t (cur = t&1; stages target buf cur = (t+2)&1, data for tile t+2):
//   P1: rd A(mi0-3)+B(ni0-1) | bar | MFMA Q(0-3,0-1)          | bar
//   P2: rd A(mi4-7)+B(ni2-3) | bar | MFMA Q(4-7,2-3)          | bar   <- consumes A1,B1
//   P3: stage Ah0,Ah1,Bh0(t+2)     | MFMA Q(4-7,0-1) regs     | bar
//   P4: stage Bh1(t+2)             | MFMA Q(0-3,2-3) regs     | vmcnt(8) | bar
// Race-freedom: ALL ds_reads of tile t are lgkm-consumed by MFMA within P1/P2 (compiler-
// tracked C++ reads), and the P2-end barrier orders every wave's consumption before any
// P3 stage into the same buffer. vmcnt ledger (R2/R4-verified): 8 loads/tile; at P4's
// vmcnt(8), tile t+1's 8 landed, tile t+2's 8 in flight. Tail drains vmcnt(0).
__device__ __forceinline__ void gemm256_core(const u16* __restrict__ AG,
                                             const u16* __restrict__ BG,
                                             int tile_m, int tile_n,
                                             u16* ldsA, u16* ldsB,
                                             f32x4 (*acc)[4]) {
    int tid  = threadIdx.x;
    int wave = tid >> 6, lane = tid & 63;
    int wr = wave >> 2, wc = wave & 3;
    int q = lane >> 4;
    // staging: thread covers 16B slot (tid&7) of local row (tid>>3) within each 64-row pass.
    // Source col-slot pre-swizzled: (tid&7) ^ (row&7); row&7 == (tid>>3)&7 for all passes.
    int srow = tid >> 3;
    int scol = ((tid & 7) ^ (srow & 7)) * 8;
    const u16* gA = AG + (size_t)(tile_m + srow) * D_DIM + scol;
    const u16* gB = BG + (size_t)(tile_n + srow) * D_DIM + scol;
    int ldst = wave * 512;   // u16: wave-uniform gload dest base within an 8KB 64-row pass
    // fragment read: local row m, u16 off = m*64 + ((ks*4+q)^(m&7))*8 ; m&7 == lane&7
    int aRow = wr * 128 + (lane & 15);
    int bRow = wc * 64 + (lane & 15);
    int x7 = lane & 7;
    int s0 = (q ^ x7) * 8;          // ks=0 slot
    int s1 = ((4 | q) ^ x7) * 8;    // ks=1 slot

// stage one 128-row half (2 gloads/thread): rows half*128 + {0,64} + srow, k-cols koff..+63
#define STG2(ldsb, gsrc, koff, half)                                         \
    do {                                                                     \
        GLOAD16((gsrc) + (size_t)((half) * 128) * D_DIM + (koff),            \
                (ldsb) + (half) * 8192 + ldst);                              \
        GLOAD16((gsrc) + (size_t)((half) * 128 + 64) * D_DIM + (koff),       \
                (ldsb) + (half) * 8192 + 4096 + ldst);                       \
    } while (0)

#define RD4A(dst, base, mo)                                                  \
    do {                                                                     \
        _Pragma("unroll") for (int mi_ = 0; mi_ < 4; mi_++) {                \
            dst[mi_][0] = *(const bf16x8*)((base) + ((mo) + mi_) * 1024 + s0); \
            dst[mi_][1] = *(const bf16x8*)((base) + ((mo) + mi_) * 1024 + s1); \
        }                                                                    \
    } while (0)

#define RD2B(dst, base, no)                                                  \
    do {                                                                     \
        _Pragma("unroll") for (int ni_ = 0; ni_ < 2; ni_++) {                \
            dst[ni_][0] = *(const bf16x8*)((base) + ((no) + ni_) * 1024 + s0); \
            dst[ni_][1] = *(const bf16x8*)((base) + ((no) + ni_) * 1024 + s1); \
        }                                                                    \
    } while (0)

// 16 MFMA, ks-outer: adjacent instructions target different acc (dep distance 8).
// Per-acc order ks0 then ks1 -> bit-identical accumulation across rounds.
#define MMQ(Af, Bf, mo, no)                                              \
    do {                                                                 \
        __builtin_amdgcn_s_setprio(1);                                   \
        _Pragma("unroll") for (int ks_ = 0; ks_ < 2; ks_++)              \
            _Pragma("unroll") for (int mi_ = 0; mi_ < 4; mi_++)          \
                _Pragma("unroll") for (int ni_ = 0; ni_ < 2; ni_++)      \
                    acc[(mo) + mi_][(no) + ni_] =                        \
                        __builtin_amdgcn_mfma_f32_16x16x32_bf16(         \
                            Af[mi_][ks_], Bf[ni_][ks_],                  \
                            acc[(mo) + mi_][(no) + ni_], 0, 0, 0);       \
        __builtin_amdgcn_s_setprio(0);                                   \
    } while (0)

    // prologue: stage tiles 0 (buf0) and 1 (buf1), 8 loads each;
    // vmcnt(8) -> tile0 landed (tile1's 8 in flight); publish.
    STG2(ldsB, gB, 0, 0); STG2(ldsA, gA, 0, 0); STG2(ldsA, gA, 0, 1); STG2(ldsB, gB, 0, 1);
    STG2(ldsB + 16384, gB, 64, 0); STG2(ldsA + 16384, gA, 64, 0);
    STG2(ldsA + 16384, gA, 64, 1); STG2(ldsB + 16384, gB, 64, 1);
    WAITVM(8);
    BAR();

    for (int t = 0; t < NKT; t++) {
        const int cur = t & 1;                       // (t+2)&1 == cur (same buffer)
        const u16* pA = ldsA + cur * 16384 + aRow * 64;
        const u16* pB = ldsB + cur * 16384 + bRow * 64;
        u16* dA = ldsA + cur * 16384;
        u16* dB = ldsB + cur * 16384;
        const bool stg = (t + 2 < NKT);
        const size_t ko = (size_t)(t + 2) * 64;
        bf16x8 A0[4][2], A1[4][2], B0[2][2], B1[2][2];
        // ---- P1: 12 ds_read -> MFMA consuming A0,B0
        RD4A(A0, pA, 0);
        RD2B(B0, pB, 0);
        BAR();
        MMQ(A0, B0, 0, 0);
        BAR();
        // ---- P2: 12 ds_read -> MFMA consuming A1,B1 (all tile-t LDS reads now consumed)
        RD4A(A1, pA, 4);
        RD2B(B1, pB, 2);
        BAR();
        MMQ(A1, B1, 4, 2);
        BAR();
        // ---- P3: buf cur fully consumed by every wave (P2-end barrier) -> stage t+2
        if (stg) { STG2(dA, gA, ko, 0); STG2(dA, gA, ko, 1); STG2(dB, gB, ko, 0); }
        MMQ(A1, B0, 4, 0);   // regs only
        BAR();
        // ---- P4: last stage; reg MFMA covers load latency; counted vmcnt
        if (stg) STG2(dB, gB, ko, 1);
        MMQ(A0, B1, 0, 2);   // regs only
        if (t + 2 < NKT) { WAITVM(8); }              // tile t+1 landed; t+2 in flight
        else if (t + 1 < NKT) { WAITVM(0); }         // tail: land final tile
        BAR();
    }
#undef STG2
#undef RD4A
#undef RD2B
#undef MMQ
}

// ---------------- GEMM1: alpha=sigmoid(xn@Wf^T+bf+ab); writes la (bf16) and, fused,
// per-chunk scan aggregates S = sum(la over 32 t), Tb = sum(bx*exp(local inclusive cumsum)).
// Wave owns 128x64 = 4 chunks (mi pairs); prefix over q=lane>>4 via shfl_up as before.
__global__ __launch_bounds__(512, 2) void gemm1_kernel(const u16* __restrict__ xn,
                                                       const u16* __restrict__ Wfc,
                                                       const float* __restrict__ bf_,
                                                       const float* __restrict__ ab,
                                                       const float* __restrict__ bs,
                                                       u16* __restrict__ out_la,
                                                       float* __restrict__ Sg,
                                                       float* __restrict__ Tg) {
    __shared__ __align__(16) u16 ldsA[2][16384];
    __shared__ __align__(16) u16 ldsB[2][16384];
    // bijective XCD chunking: 256 blocks = 8 XCD x (8 m-panels x 4 n-tiles)
    int flat = blockIdx.y * 4 + blockIdx.x;
    int xcd = flat & 7, p = flat >> 3;
    int tile_m = (xcd * 8 + (p >> 2)) * 256;
    int tile_n = (p & 3) * 256;
    f32x4 acc[8][4] = {};
    gemm256_core(xn, Wfc, tile_m, tile_n, &ldsA[0][0], &ldsB[0][0], acc);

    // epilogue: C/D layout col=lane&15 (+ni*16), row=(lane>>4)*4+r (+mi*16) [m89-verified]
    int tid = threadIdx.x, wave = tid >> 6, lane = tid & 63;
    int wr = wave >> 2, wc = wave & 3;
    float abv = ab[0], bsv = bs[0];
    int q = lane >> 4, l = lane & 15;
    #pragma unroll
    for (int ni = 0; ni < 4; ni++) {
        int col = tile_n + wc * 64 + ni * 16 + l;
        float bcol = bf_[col];
        #pragma unroll
        for (int ch = 0; ch < 4; ch++) {   // chunk (32 rows) = mi pair {2ch, 2ch+1}
            float lav[2][4], bxv[2][4];
            #pragma unroll
            for (int h = 0; h < 2; h++) {
                int mi = 2 * ch + h;
                #pragma unroll
                for (int r = 0; r < 4; r++) {
                    int row = tile_m + wr * 128 + mi * 16 + q * 4 + r;
                    float z = acc[mi][ni][r] + bcol + abv;
                    float alpha = 1.f / (1.f + __expf(-z));
                    float la_ = __logf(alpha + 1e-8f);
                    float xv = bf2f(xn[(size_t)row * D_DIM + col]);
                    lav[h][r] = la_;
                    bxv[h][r] = bsv * (1.f - alpha) * xv;
                    out_la[(size_t)row * D_DIM + col] = f2bf(la_);
                }
            }
            // wave-local chunk scan: t = h*16 + q*4 + r
            float s0 = lav[0][0] + lav[0][1] + lav[0][2] + lav[0][3];
            float s1 = lav[1][0] + lav[1][1] + lav[1][2] + lav[1][3];
            float x0 = s0, x1 = s1, y;
            y = __shfl_up(x0, 16, 64); if (q >= 1) x0 += y;
            y = __shfl_up(x0, 32, 64); if (q >= 2) x0 += y;
            y = __shfl_up(x1, 16, 64); if (q >= 1) x1 += y;
            y = __shfl_up(x1, 32, 64); if (q >= 2) x1 += y;
            float t0 = __shfl(x0, l + 48, 64);   // totals from q=3 lane
            float t1 = __shfl(x1, l + 48, 64);
            float e0 = x0 - s0, e1 = x1 - s1;    // exclusive prefixes over q
            float pr = e0, Tp = 0.f;
            #pragma unroll
            for (int r = 0; r < 4; r++) { pr += lav[0][r]; Tp += bxv[0][r] * __expf(pr); }
            pr = t0 + e1;
            #pragma unroll
            for (int r = 0; r < 4; r++) { pr += lav[1][r]; Tp += bxv[1][r] * __expf(pr); }
            Tp += __shfl_xor(Tp, 16, 64);
            Tp += __shfl_xor(Tp, 32, 64);
            if (q == 0) {
                int cidx = ((tile_m + wr * 128) >> 5) + ch;   // = b*NCHUNK + chunk
                Sg[(size_t)cidx * D_DIM + col] = t0 + t1;
                Tg[(size_t)cidx * D_DIM + col] = Tp;
            }
        }
    }
}

// ---------------- combine: per (b,d), prefix over 128 chunks. m = la[b, t=0, d]. ----------
__global__ __launch_bounds__(1024) void scan_combine(const u16* __restrict__ la,
                                                     const float* __restrict__ S,
                                                     const float* __restrict__ Tb,
                                                     float* __restrict__ Of,
                                                     float* __restrict__ SSp) {
    __shared__ float lsS[NWAVE_C][64], lsW[NWAVE_C][64];
    int b = blockIdx.x >> 4;
    int dg = blockIdx.x & 15;
    int wave = threadIdx.x >> 6, lane = threadIdx.x & 63;
    int d = dg * 64 + lane;
    float m = bf2f(la[(size_t)(b * T_DIM) * D_DIM + d]);   // cumsum[0] ~= global max
    size_t base = ((size_t)b * NCHUNK) * D_DIM + d;
    int c0 = wave * SEG;

    float OfR[SEG], wR[SEG];
    float Or = 0.f, w = 0.f;
    #pragma unroll
    for (int j = 0; j < SEG; j++) {
        size_t ci = base + (size_t)(c0 + j) * D_DIM;
        OfR[j] = Or;
        wR[j]  = w;
        w  += __expf(Or) * Tb[ci];
        Or += S[ci];
    }
    lsS[wave][lane] = Or; lsW[wave][lane] = w;
    __syncthreads();

    float o = 0.f, s = 0.f, myO = 0.f, myS = 0.f;
    #pragma unroll
    for (int w2 = 0; w2 < NWAVE_C; w2++) {
        if (w2 == wave) { myO = o; myS = s; }
        s += __expf(o - m) * lsW[w2][lane];
        o += lsS[w2][lane];
    }

    float em = __expf(myO - m);
    #pragma unroll
    for (int j = 0; j < SEG; j++) {
        size_t ci = base + (size_t)(c0 + j) * D_DIM;
        Of[ci]  = myO + OfR[j] - m;
        SSp[ci] = myS + em * wR[j];
    }
}

// ---------------- final: scale=exp(Of+p), s_star=SSp+cumsum, out=s_star/(scale+1e-8) -----
// 4 cols/thread; osc aliases xn (reads at idx precede the write at idx, same thread).
__global__ __launch_bounds__(256) void scan_final(const u16* __restrict__ la,
                                                  const u16* __restrict__ xn,
                                                  const float* __restrict__ bs,
                                                  const float* __restrict__ Of,
                                                  const float* __restrict__ SSp,
                                                  u16* __restrict__ osc) {
    int bc = blockIdx.x;
    int b = bc >> 7, c = bc & (NCHUNK - 1);
    int col0 = threadIdx.x * 4;
    float bsv = bs[0];
    size_t base = ((size_t)(b * T_DIM + c * CHUNK)) * D_DIM + col0;
    size_t ci = ((size_t)(b * NCHUNK + c)) * D_DIM + col0;
    float ofs[4], ss[4], p[4];
    #pragma unroll
    for (int j = 0; j < 4; j++) { ofs[j] = Of[ci + j]; ss[j] = SSp[ci + j]; p[j] = 0.f; }
    #pragma unroll 8
    for (int t = 0; t < CHUNK; t++) {
        size_t idx = base + (size_t)t * D_DIM;
        ushort4 lv = *(const ushort4*)(la + idx);
        ushort4 xv = *(const ushort4*)(xn + idx);
        u16 lvs[4] = {lv.x, lv.y, lv.z, lv.w};
        u16 xvs[4] = {xv.x, xv.y, xv.z, xv.w};
        u16 os[4];
        #pragma unroll
        for (int j = 0; j < 4; j++) {
            float lav = bf2f(lvs[j]);
            p[j] += lav;
            float scv = __expf(ofs[j] + p[j]);
            float bx = bsv * (1.f - __expf(lav)) * bf2f(xvs[j]);
            ss[j] += bx * scv;
            os[j] = f2bf(ss[j] / (scv + 1e-8f));
        }
        ushort4 o; o.x = os[0]; o.y = os[1]; o.z = os[2]; o.w = os[3];
        *(ushort4*)(osc + idx) = o;
    }
}

// ---------------- GEMM2: out = 0.05*tanh(osc@Wr^T + br) + x ----------------
__global__ __launch_bounds__(512, 2) void gemm2_kernel(const u16* __restrict__ A,
                                                       const u16* __restrict__ Bm,
                                                       const float* __restrict__ bias,
                                                       const float* __restrict__ resid,
                                                       float* __restrict__ out_f) {
    __shared__ __align__(16) u16 ldsA[2][16384];
    __shared__ __align__(16) u16 ldsB[2][16384];
    int flat = blockIdx.y * 4 + blockIdx.x;
    int xcd = flat & 7, p = flat >> 3;
    int tile_m = (xcd * 8 + (p >> 2)) * 256;
    int tile_n = (p & 3) * 256;
    f32x4 acc[8][4] = {};
    gemm256_core(A, Bm, tile_m, tile_n, &ldsA[0][0], &ldsB[0][0], acc);

    int tid = threadIdx.x, wave = tid >> 6, lane = tid & 63;
    int wr = wave >> 2, wc = wave & 3;
    int q = lane >> 4, l = lane & 15;
    #pragma unroll
    for (int mi = 0; mi < 8; mi++) {
        #pragma unroll
        for (int r = 0; r < 4; r++) {
            int row = tile_m + wr * 128 + mi * 16 + q * 4 + r;
            #pragma unroll
            for (int ni = 0; ni < 4; ni++) {
                int col = tile_n + wc * 64 + ni * 16 + l;
                size_t idx = (size_t)row * D_DIM + col;
                float g = fast_tanh(acc[mi][ni][r] + bias[col]);
                out_f[idx] = 0.05f * g + resid[idx];
            }
        }
    }
}

extern "C" void kernel_launch(void* const* d_in, const int* in_sizes, int n_in,
                              void* d_out, int out_size, void* d_ws, size_t ws_size,
                              hipStream_t stream) {
    const float* x   = (const float*)d_in[0];
    const float* lnw = (const float*)d_in[1];
    const float* lnb = (const float*)d_in[2];
    const float* Wf  = (const float*)d_in[3];
    const float* bf_ = (const float*)d_in[4];
    const float* Wr  = (const float*)d_in[5];
    const float* br  = (const float*)d_in[6];
    const float* ab  = (const float*)d_in[7];
    const float* bs  = (const float*)d_in[8];
    float* out = (float*)d_out;

    // workspace (76 MB):
    //   xn  : [ 0,32MB) bf16 layernorm out; later overwritten in-place by scan output
    //   la  : [32,64MB) bf16 log(alpha+1e-8) from GEMM1
    //   Wfc : [64,66MB)  Wrc : [66,68MB)
    //   S,Tb,Of,SSp : 4 x 2MB fp32 at [68,76MB)
    char* w = (char*)d_ws;
    u16* xn  = (u16*)w;
    u16* la  = (u16*)(w + (size_t)33554432);
    u16* Wfc = (u16*)(w + (size_t)67108864);
    u16* Wrc = (u16*)(w + (size_t)69206016);
    float* S   = (float*)(w + (size_t)71303168);
    float* Tb  = S  + 524288;
    float* Of  = Tb + 524288;
    float* SSp = Of + 524288;
    u16* osc = xn;

    ln_conv_kernel<<<dim3(2048 + M_DIM / 4), dim3(256), 0, stream>>>(
        x, lnw, lnb, xn, Wf, Wr, Wfc, Wrc);
    gemm1_kernel<<<dim3(D_DIM / 256, M_DIM / 256), dim3(512), 0, stream>>>(
        xn, Wfc, bf_, ab, bs, la, S, Tb);
    scan_combine<<<dim3(B_DIM * 16), dim3(1024), 0, stream>>>(la, S, Tb, Of, SSp);
    scan_final<<<dim3(B_DIM * NCHUNK), dim3(256), 0, stream>>>(la, xn, bs, Of, SSp, osc);
    gemm2_kernel<<<dim3(D_DIM / 256, M_DIM / 256), dim3(512), 0, stream>>>(
        osc, Wrc, br, x, out);
}

// Round 9
// 268.638 us; speedup vs baseline: 1.0361x; 1.0361x over previous
//
#include <hip/hip_runtime.h>

// B=4, T=4096, D=1024. Inputs/outputs fp32. GEMM in bf16 MFMA.
// Pipeline: ln_conv -> gemm1 (+fused per-chunk scan aggregates) -> combine -> final -> gemm2.
// Numerics: la = log(alpha+1e-8) <= ~1e-8, so global max of cumsum ~= la[t=0] (error <= 4e-5);
// m is read from la row t=0 in combine; no max machinery anywhere.
// R9: depth-4 pipeline. BK=32, 4 LDS buffers/operand (same 128 KiB), 3 K-tiles in flight at
//     the counted vmcnt (7400 cy slack vs R8's 1-tile 2500) -- tests the HBM/L2-jitter
//     hypothesis left after R4/R8 proved barrier count and phase granularity null at 17%
//     MfmaUtil. ONE barrier per K-tile. setprio dropped (m190: negative on lockstep GEMM).
//     K consumed in identical ascending 32-chunks per acc -> bit-identical numerics.
//     gemm1 epilogue: xn block [256][256] staged into the (now free) 128 KiB LDS via
//     coalesced global_load_lds (replaces 16.7M scattered scalar u16 global loads).
#define D_DIM 1024
#define B_DIM 4
#define T_DIM 4096
#define M_DIM (B_DIM * T_DIM)   // 16384 rows
#define CHUNK 32
#define NCHUNK (T_DIM / CHUNK)  // 128
#define NWAVE_C 16              // waves per combine block
#define SEG (NCHUNK / NWAVE_C)  // 8 chunks per wave in combine
#define NKT (D_DIM / 32)        // 32 K-tiles of 32

typedef unsigned short u16;
typedef __attribute__((ext_vector_type(8))) __bf16 bf16x8;
typedef __attribute__((ext_vector_type(4))) float f32x4;

__device__ __forceinline__ float bf2f(u16 u) {
    union { unsigned int i; float f; } v;
    v.i = ((unsigned int)u) << 16;
    return v.f;
}
__device__ __forceinline__ u16 f2bf(float f) {
    union { float f; unsigned int i; } v;
    v.f = f;
    unsigned int u = v.i;
    unsigned int r = (u + 0x7fffu + ((u >> 16) & 1u)) >> 16;
    return (u16)r;
}
__device__ __forceinline__ float fast_tanh(float v) {
    float e = __expf(2.f * v);
    return 1.f - 2.f / (e + 1.f);
}

#define GLOAD16(g, l)                                                   \
    __builtin_amdgcn_global_load_lds(                                   \
        (const __attribute__((address_space(1))) void*)(g),             \
        (__attribute__((address_space(3))) void*)(l), 16, 0, 0)

// Plain barrier between compiler memory fences (no sched_barrier -- m141/R3 lesson).
#define BAR()                                      \
    do {                                           \
        asm volatile("" ::: "memory");             \
        __builtin_amdgcn_s_barrier();              \
        asm volatile("" ::: "memory");             \
    } while (0)

#define WAITVM(N) asm volatile("s_waitcnt vmcnt(" #N ")" ::: "memory")

// ---------------- fused weight-convert (blocks 0..2047) + wave-per-row LayerNorm ----------
__global__ __launch_bounds__(256) void ln_conv_kernel(const float* __restrict__ x,
                                                      const float* __restrict__ w,
                                                      const float* __restrict__ b,
                                                      u16* __restrict__ xn,
                                                      const float* __restrict__ Wf,
                                                      const float* __restrict__ Wr,
                                                      u16* __restrict__ da,
                                                      u16* __restrict__ db) {
    int tid = threadIdx.x;
    if (blockIdx.x < 2048) {            // convert: 2 x 262144 float4s
        int i = blockIdx.x * 256 + tid;
        const float* s = (i < 262144) ? Wf : Wr;
        u16* dp = (i < 262144) ? da : db;
        int j = i & 262143;
        float4 v = ((const float4*)s)[j];
        ushort4 o;
        o.x = f2bf(v.x); o.y = f2bf(v.y); o.z = f2bf(v.z); o.w = f2bf(v.w);
        ((ushort4*)dp)[j] = o;
        return;
    }
    // LN: one wave per row, 4 rows per block, no __syncthreads
    int wv = tid >> 6, lane = tid & 63;
    int row = (blockIdx.x - 2048) * 4 + wv;
    const float4* xr = (const float4*)(x + (size_t)row * D_DIM);
    float4 xv[4];
    #pragma unroll
    for (int k = 0; k < 4; k++) xv[k] = xr[lane + 64 * k];
    float s = 0.f, s2 = 0.f;
    #pragma unroll
    for (int k = 0; k < 4; k++) {
        s  += xv[k].x + xv[k].y + xv[k].z + xv[k].w;
        s2 += xv[k].x * xv[k].x + xv[k].y * xv[k].y
            + xv[k].z * xv[k].z + xv[k].w * xv[k].w;
    }
    #pragma unroll
    for (int o = 1; o < 64; o <<= 1) {
        s  += __shfl_xor(s, o, 64);
        s2 += __shfl_xor(s2, o, 64);
    }
    float mu = s * (1.0f / D_DIM);
    float var = s2 * (1.0f / D_DIM) - mu * mu;
    float rs = rsqrtf(var + 1e-5f);
    ushort4* xo = (ushort4*)(xn + (size_t)row * D_DIM);
    #pragma unroll
    for (int k = 0; k < 4; k++) {
        float4 wv4 = ((const float4*)w)[lane + 64 * k];
        float4 bv4 = ((const float4*)b)[lane + 64 * k];
        ushort4 o;
        o.x = f2bf((xv[k].x - mu) * rs * wv4.x + bv4.x);
        o.y = f2bf((xv[k].y - mu) * rs * wv4.y + bv4.y);
        o.z = f2bf((xv[k].z - mu) * rs * wv4.z + bv4.z);
        o.w = f2bf((xv[k].w - mu) * rs * wv4.w + bv4.w);
        xo[lane + 64 * k] = o;
    }
}

// ---------------- 256x256 BK=32 depth-4 pipelined GEMM core (fills acc[8][4]) ------------
// A [M][1024], B [N][1024] row-major bf16 (C = A.B^T slice). 512 thr = 8 waves (2m x 4n).
// LDS: 4 buffers/operand x [256 rows][32 cols] u16 (16 KB each) = 128 KiB total.
// Staging (per operand, per tile: 2 gloads/thread): wave-instr (w,j) covers LDS bytes
//   w*2048 + j*1024 + lane*16 -> row = w*32 + j*16 + (lane>>2), 16B-slot = lane&3.
//   Source col-slot pre-swizzled: slot' = (lane&3) ^ (row&3), row&3 == (lane>>2)&3.
// Fragment read (16x16x32): row fr = lane&15 (+16*mi), slot q = lane>>4, LDS slot
//   q ^ (fr&3) -> contents = source slot q (swizzle cancels). Dense 1024B permutation
//   per 16-row group -> conflict-free ds_read_b128.
// Loop per K-tile t (buf c = t&3): {12 ds_read, 32 MFMA (ni-inner, dep distance 4)},
//   stage tile t+3 into buf (t+3)&3 (last read 1 iter ago, 1 barrier crossed), WAITVM(8)
//   (lands t+1; t+2,t+3 = 8 loads in flight), BAR (publish). ONE barrier per tile.
// Ledger: 4 loads/thread/tile. Prologue stages 0,1,2 (12), vmcnt(8) lands tile 0.
// Tail: t=NKT-3 -> vmcnt(4) lands t+1; t=NKT-2 -> vmcnt(0); t=NKT-1 -> none.
// Accumulation: one MFMA per acc per 32-K-chunk, chunks ascending == R8's order exactly.
__device__ __forceinline__ void gemm256_core(const u16* __restrict__ AG,
                                             const u16* __restrict__ BG,
                                             int tile_m, int tile_n,
                                             u16* ldsA, u16* ldsB,
                                             f32x4 (*acc)[4]) {
    int tid  = threadIdx.x;
    int wave = tid >> 6, lane = tid & 63;
    int wr = wave >> 2, wc = wave & 3;
    // staging addresses
    int lrow = lane >> 2;                       // 0..15
    int sswz = (lane & 3) ^ (lrow & 3);         // source 16B col-slot
    const u16* gA = AG + (size_t)(tile_m + wave * 32 + lrow) * D_DIM + sswz * 8;
    const u16* gB = BG + (size_t)(tile_n + wave * 32 + lrow) * D_DIM + sswz * 8;
    int ldst = wave * 1024 + lane * 8;          // u16: wave-instr base + lane*16B
    // fragment addresses
    int fr = lane & 15, q = lane >> 4;
    int sw = (q ^ (lane & 3)) * 8;              // u16 offset of swizzled k-slot
    const u16* pAb = ldsA + (wr * 128 + fr) * 32 + sw;
    const u16* pBb = ldsB + (wc * 64 + fr) * 32 + sw;

// stage one operand tile tt (2 gloads): rows wave*32 + {0,16} + lrow, k-cols tt*32..+31
#define STG(ldsb, gsrc, tt)                                                  \
    do {                                                                     \
        GLOAD16((gsrc) + (size_t)(tt) * 32,                                  \
                (ldsb) + ((tt) & 3) * 8192 + ldst);                          \
        GLOAD16((gsrc) + (size_t)(tt) * 32 + (size_t)16 * D_DIM,             \
                (ldsb) + ((tt) & 3) * 8192 + 512 + ldst);                    \
    } while (0)

    // prologue: stage tiles 0,1,2 (12 loads); vmcnt(8) lands tile 0; publish.
    STG(ldsA, gA, 0); STG(ldsB, gB, 0);
    STG(ldsA, gA, 1); STG(ldsB, gB, 1);
    STG(ldsA, gA, 2); STG(ldsB, gB, 2);
    WAITVM(8);
    BAR();

    for (int t = 0; t < NKT; t++) {
        const int c = t & 3;
        const u16* pA = pAb + c * 8192;
        const u16* pB = pBb + c * 8192;
        bf16x8 Af[8], Bf[4];
        #pragma unroll
        for (int ni = 0; ni < 4; ni++) Bf[ni] = *(const bf16x8*)(pB + ni * 512);
        #pragma unroll
        for (int mi = 0; mi < 8; mi++) Af[mi] = *(const bf16x8*)(pA + mi * 512);
        #pragma unroll
        for (int mi = 0; mi < 8; mi++)
            #pragma unroll
            for (int ni = 0; ni < 4; ni++)
                acc[mi][ni] = __builtin_amdgcn_mfma_f32_16x16x32_bf16(
                    Af[mi], Bf[ni], acc[mi][ni], 0, 0, 0);
        if (t + 3 < NKT) {
            STG(ldsA, gA, t + 3);
            STG(ldsB, gB, t + 3);
            WAITVM(8);          // lands tile t+1; t+2,t+3 (8 loads) in flight
        } else if (t + 2 < NKT) {
            WAITVM(4);          // lands tile t+1; t+2 in flight
        } else if (t + 1 < NKT) {
            WAITVM(0);          // lands final tile
        }
        BAR();
    }
#undef STG
}

// ---------------- GEMM1: alpha=sigmoid(xn@Wf^T+bf+ab); writes la (bf16) and, fused,
// per-chunk scan aggregates S = sum(la over 32 t), Tb = sum(bx*exp(local inclusive cumsum)).
// Wave owns 128x64 = 4 chunks (mi pairs); prefix over q=lane>>4 via shfl_up as before.
// Epilogue xn access: [256][256] u16 block staged into the freed 128 KiB LDS (coalesced
// gload_lds, XOR-swizzled 16B slots both sides), then scalar LDS reads.
__global__ __launch_bounds__(512, 2) void gemm1_kernel(const u16* __restrict__ xn,
                                                       const u16* __restrict__ Wfc,
                                                       const float* __restrict__ bf_,
                                                       const float* __restrict__ ab,
                                                       const float* __restrict__ bs,
                                                       u16* __restrict__ out_la,
                                                       float* __restrict__ Sg,
                                                       float* __restrict__ Tg) {
    __shared__ __align__(16) u16 lds[65536];   // 128 KiB
    u16* ldsA = lds;
    u16* ldsB = lds + 32768;
    // bijective XCD chunking: 256 blocks = 8 XCD x (8 m-panels x 4 n-tiles)
    int flat = blockIdx.y * 4 + blockIdx.x;
    int xcd = flat & 7, p = flat >> 3;
    int tile_m = (xcd * 8 + (p >> 2)) * 256;
    int tile_n = (p & 3) * 256;
    f32x4 acc[8][4] = {};
    gemm256_core(xn, Wfc, tile_m, tile_n, ldsA, ldsB, acc);

    int tid = threadIdx.x, wave = tid >> 6, lane = tid & 63;
    int wr = wave >> 2, wc = wave & 3;
    int q = lane >> 4, l = lane & 15;
    // ---- stage xn[tile_m..+255][tile_n..+255] into lds (row-major 256 u16/row, swizzled
    // 16B slots: LDS slot s of row r holds source slot s^(r&3)). Loop K-loop's final BAR
    // ordered all LDS reads before this overwrite.
    #pragma unroll
    for (int j = 0; j < 16; j++) {
        int xrow = wave * 32 + j * 2 + (lane >> 5);
        int xslot = (lane & 31) ^ (xrow & 3);
        GLOAD16(xn + (size_t)(tile_m + xrow) * D_DIM + tile_n + xslot * 8,
                lds + wave * 8192 + j * 512 + lane * 8);
    }
    WAITVM(0);
    BAR();

    // epilogue: C/D layout col=lane&15 (+ni*16), row=(lane>>4)*4+r (+mi*16) [m89-verified]
    float abv = ab[0], bsv = bs[0];
    #pragma unroll
    for (int ni = 0; ni < 4; ni++) {
        int col = tile_n + wc * 64 + ni * 16 + l;
        float bcol = bf_[col];
        #pragma unroll
        for (int ch = 0; ch < 4; ch++) {   // chunk (32 rows) = mi pair {2ch, 2ch+1}
            float lav[2][4], bxv[2][4];
            #pragma unroll
            for (int h = 0; h < 2; h++) {
                int mi = 2 * ch + h;
                #pragma unroll
                for (int r = 0; r < 4; r++) {
                    int rl = wr * 128 + mi * 16 + q * 4 + r;       // local row
                    int cl = wc * 64 + ni * 16 + l;                // local col
                    int row = tile_m + rl;
                    float z = acc[mi][ni][r] + bcol + abv;
                    float alpha = 1.f / (1.f + __expf(-z));
                    float la_ = __logf(alpha + 1e-8f);
                    float xv = bf2f(lds[rl * 256 + (((cl >> 3) ^ (rl & 3)) * 8) + (cl & 7)]);
                    lav[h][r] = la_;
                    bxv[h][r] = bsv * (1.f - alpha) * xv;
                    out_la[(size_t)row * D_DIM + col] = f2bf(la_);
                }
            }
            // wave-local chunk scan: t = h*16 + q*4 + r
            float s0 = lav[0][0] + lav[0][1] + lav[0][2] + lav[0][3];
            float s1 = lav[1][0] + lav[1][1] + lav[1][2] + lav[1][3];
            float x0 = s0, x1 = s1, y;
            y = __shfl_up(x0, 16, 64); if (q >= 1) x0 += y;
            y = __shfl_up(x0, 32, 64); if (q >= 2) x0 += y;
            y = __shfl_up(x1, 16, 64); if (q >= 1) x1 += y;
            y = __shfl_up(x1, 32, 64); if (q >= 2) x1 += y;
            float t0 = __shfl(x0, l + 48, 64);   // totals from q=3 lane
            float t1 = __shfl(x1, l + 48, 64);
            float e0 = x0 - s0, e1 = x1 - s1;    // exclusive prefixes over q
            float pr = e0, Tp = 0.f;
            #pragma unroll
            for (int r = 0; r < 4; r++) { pr += lav[0][r]; Tp += bxv[0][r] * __expf(pr); }
            pr = t0 + e1;
            #pragma unroll
            for (int r = 0; r < 4; r++) { pr += lav[1][r]; Tp += bxv[1][r] * __expf(pr); }
            Tp += __shfl_xor(Tp, 16, 64);
            Tp += __shfl_xor(Tp, 32, 64);
            if (q == 0) {
                int cidx = ((tile_m + wr * 128) >> 5) + ch;   // = b*NCHUNK + chunk
                Sg[(size_t)cidx * D_DIM + col] = t0 + t1;
                Tg[(size_t)cidx * D_DIM + col] = Tp;
            }
        }
    }
}

// ---------------- combine: per (b,d), prefix over 128 chunks. m = la[b, t=0, d]. ----------
__global__ __launch_bounds__(1024) void scan_combine(const u16* __restrict__ la,
                                                     const float* __restrict__ S,
                                                     const float* __restrict__ Tb,
                                                     float* __restrict__ Of,
                                                     float* __restrict__ SSp) {
    __shared__ float lsS[NWAVE_C][64], lsW[NWAVE_C][64];
    int b = blockIdx.x >> 4;
    int dg = blockIdx.x & 15;
    int wave = threadIdx.x >> 6, lane = threadIdx.x & 63;
    int d = dg * 64 + lane;
    float m = bf2f(la[(size_t)(b * T_DIM) * D_DIM + d]);   // cumsum[0] ~= global max
    size_t base = ((size_t)b * NCHUNK) * D_DIM + d;
    int c0 = wave * SEG;

    float OfR[SEG], wR[SEG];
    float Or = 0.f, w = 0.f;
    #pragma unroll
    for (int j = 0; j < SEG; j++) {
        size_t ci = base + (size_t)(c0 + j) * D_DIM;
        OfR[j] = Or;
        wR[j]  = w;
        w  += __expf(Or) * Tb[ci];
        Or += S[ci];
    }
    lsS[wave][lane] = Or; lsW[wave][lane] = w;
    __syncthreads();

    float o = 0.f, s = 0.f, myO = 0.f, myS = 0.f;
    #pragma unroll
    for (int w2 = 0; w2 < NWAVE_C; w2++) {
        if (w2 == wave) { myO = o; myS = s; }
        s += __expf(o - m) * lsW[w2][lane];
        o += lsS[w2][lane];
    }

    float em = __expf(myO - m);
    #pragma unroll
    for (int j = 0; j < SEG; j++) {
        size_t ci = base + (size_t)(c0 + j) * D_DIM;
        Of[ci]  = myO + OfR[j] - m;
        SSp[ci] = myS + em * wR[j];
    }
}

// ---------------- final: scale=exp(Of+p), s_star=SSp+cumsum, out=s_star/(scale+1e-8) -----
// 4 cols/thread; osc aliases xn (reads at idx precede the write at idx, same thread).
__global__ __launch_bounds__(256) void scan_final(const u16* __restrict__ la,
                                                  const u16* __restrict__ xn,
                                                  const float* __restrict__ bs,
                                                  const float* __restrict__ Of,
                                                  const float* __restrict__ SSp,
                                                  u16* __restrict__ osc) {
    int bc = blockIdx.x;
    int b = bc >> 7, c = bc & (NCHUNK - 1);
    int col0 = threadIdx.x * 4;
    float bsv = bs[0];
    size_t base = ((size_t)(b * T_DIM + c * CHUNK)) * D_DIM + col0;
    size_t ci = ((size_t)(b * NCHUNK + c)) * D_DIM + col0;
    float ofs[4], ss[4], p[4];
    #pragma unroll
    for (int j = 0; j < 4; j++) { ofs[j] = Of[ci + j]; ss[j] = SSp[ci + j]; p[j] = 0.f; }
    #pragma unroll 8
    for (int t = 0; t < CHUNK; t++) {
        size_t idx = base + (size_t)t * D_DIM;
        ushort4 lv = *(const ushort4*)(la + idx);
        ushort4 xv = *(const ushort4*)(xn + idx);
        u16 lvs[4] = {lv.x, lv.y, lv.z, lv.w};
        u16 xvs[4] = {xv.x, xv.y, xv.z, xv.w};
        u16 os[4];
        #pragma unroll
        for (int j = 0; j < 4; j++) {
            float lav = bf2f(lvs[j]);
            p[j] += lav;
            float scv = __expf(ofs[j] + p[j]);
            float bx = bsv * (1.f - __expf(lav)) * bf2f(xvs[j]);
            ss[j] += bx * scv;
            os[j] = f2bf(ss[j] / (scv + 1e-8f));
        }
        ushort4 o; o.x = os[0]; o.y = os[1]; o.z = os[2]; o.w = os[3];
        *(ushort4*)(osc + idx) = o;
    }
}

// ---------------- GEMM2: out = 0.05*tanh(osc@Wr^T + br) + x ----------------
__global__ __launch_bounds__(512, 2) void gemm2_kernel(const u16* __restrict__ A,
                                                       const u16* __restrict__ Bm,
                                                       const float* __restrict__ bias,
                                                       const float* __restrict__ resid,
                                                       float* __restrict__ out_f) {
    __shared__ __align__(16) u16 lds[65536];
    u16* ldsA = lds;
    u16* ldsB = lds + 32768;
    int flat = blockIdx.y * 4 + blockIdx.x;
    int xcd = flat & 7, p = flat >> 3;
    int tile_m = (xcd * 8 + (p >> 2)) * 256;
    int tile_n = (p & 3) * 256;
    f32x4 acc[8][4] = {};
    gemm256_core(A, Bm, tile_m, tile_n, ldsA, ldsB, acc);

    int tid = threadIdx.x, wave = tid >> 6, lane = tid & 63;
    int wr = wave >> 2, wc = wave & 3;
    int q = lane >> 4, l = lane & 15;
    #pragma unroll
    for (int mi = 0; mi < 8; mi++) {
        #pragma unroll
        for (int r = 0; r < 4; r++) {
            int row = tile_m + wr * 128 + mi * 16 + q * 4 + r;
            #pragma unroll
            for (int ni = 0; ni < 4; ni++) {
                int col = tile_n + wc * 64 + ni * 16 + l;
                size_t idx = (size_t)row * D_DIM + col;
                float g = fast_tanh(acc[mi][ni][r] + bias[col]);
                out_f[idx] = 0.05f * g + resid[idx];
            }
        }
    }
}

extern "C" void kernel_launch(void* const* d_in, const int* in_sizes, int n_in,
                              void* d_out, int out_size, void* d_ws, size_t ws_size,
                              hipStream_t stream) {
    const float* x   = (const float*)d_in[0];
    const float* lnw = (const float*)d_in[1];
    const float* lnb = (const float*)d_in[2];
    const float* Wf  = (const float*)d_in[3];
    const float* bf_ = (const float*)d_in[4];
    const float* Wr  = (const float*)d_in[5];
    const float* br  = (const float*)d_in[6];
    const float* ab  = (const float*)d_in[7];
    const float* bs  = (const float*)d_in[8];
    float* out = (float*)d_out;

    // workspace (76 MB):
    //   xn  : [ 0,32MB) bf16 layernorm out; later overwritten in-place by scan output
    //   la  : [32,64MB) bf16 log(alpha+1e-8) from GEMM1
    //   Wfc : [64,66MB)  Wrc : [66,68MB)
    //   S,Tb,Of,SSp : 4 x 2MB fp32 at [68,76MB)
    char* w = (char*)d_ws;
    u16* xn  = (u16*)w;
    u16* la  = (u16*)(w + (size_t)33554432);
    u16* Wfc = (u16*)(w + (size_t)67108864);
    u16* Wrc = (u16*)(w + (size_t)69206016);
    float* S   = (float*)(w + (size_t)71303168);
    float* Tb  = S  + 524288;
    float* Of  = Tb + 524288;
    float* SSp = Of + 524288;
    u16* osc = xn;

    ln_conv_kernel<<<dim3(2048 + M_DIM / 4), dim3(256), 0, stream>>>(
        x, lnw, lnb, xn, Wf, Wr, Wfc, Wrc);
    gemm1_kernel<<<dim3(D_DIM / 256, M_DIM / 256), dim3(512), 0, stream>>>(
        xn, Wfc, bf_, ab, bs, la, S, Tb);
    scan_combine<<<dim3(B_DIM * 16), dim3(1024), 0, stream>>>(la, S, Tb, Of, SSp);
    scan_final<<<dim3(B_DIM * NCHUNK), dim3(256), 0, stream>>>(la, xn, bs, Of, SSp, osc);
    gemm2_kernel<<<dim3(D_DIM / 256, M_DIM / 256), dim3(512), 0, stream>>>(
        osc, Wrc, br, x, out);
}